// Round 7
// baseline (324.466 us; speedup 1.0000x reference)
//
#include <hip/hip_runtime.h>
#include <cstdint>
#include <cstddef>

typedef __bf16 bf16_t;
typedef __bf16 bf16x8 __attribute__((ext_vector_type(8)));
typedef float  f32x4  __attribute__((ext_vector_type(4)));

#define D_MODEL 768
#define D_INNER 1536
#define D_STATE 16
#define DT_RANK 48
#define DT_K    64            // w_dt zero-padded K
#define NB      2
#define SEQ     2048
#define NTOK    (NB*SEQ)   // 4096
#define XPROJ_N (DT_RANK + 2*D_STATE)  // 80
#define LC      32
#define NCHUNK  (SEQ/LC)   // 64

// async global->LDS, 16B per lane; lds base must be wave-uniform, HW adds lane*16
typedef __attribute__((address_space(1))) void gvoid_t;
typedef __attribute__((address_space(3))) void lvoid_t;
__device__ __forceinline__ void g2lds16(const bf16_t* g, bf16_t* l) {
    __builtin_amdgcn_global_load_lds((gvoid_t*)g, (lvoid_t*)l, 16, 0, 0);
}

// ---------------- fp32 -> bf16 conversion (3 plain weights) ----------------
__global__ __launch_bounds__(256)
void cvt3_kernel(const float* __restrict__ s0, bf16_t* __restrict__ d0, int n0,
                 const float* __restrict__ s1, bf16_t* __restrict__ d1, int n1,
                 const float* __restrict__ s2, bf16_t* __restrict__ d2, int n2) {
    int i = blockIdx.x * 256 + threadIdx.x;
    if (i < n0) { d0[i] = (bf16_t)s0[i]; return; }
    i -= n0;
    if (i < n1) { d1[i] = (bf16_t)s1[i]; return; }
    i -= n1;
    if (i < n2) { d2[i] = (bf16_t)s2[i]; }
}

// dt_proj_w [1536,48] -> bf16 [1536,64], cols 48..63 zero
__global__ __launch_bounds__(256)
void cvt_pad_dt_kernel(const float* __restrict__ src, bf16_t* __restrict__ dst) {
    int i = blockIdx.x * 256 + threadIdx.x;        // over 1536*64
    if (i >= D_INNER * DT_K) return;
    int row = i >> 6, col = i & 63;
    dst[i] = (col < DT_RANK) ? (bf16_t)src[row * DT_RANK + col] : (bf16_t)0.f;
}

// ---------------- RMSNorm ----------------
__global__ __launch_bounds__(256)
void rmsnorm_kernel(const float* __restrict__ x, const float* __restrict__ w,
                    bf16_t* __restrict__ h) {
    int t = blockIdx.x;
    int tid = threadIdx.x;
    const float* xr = x + (size_t)t * D_MODEL;
    float v[3];
    float ss = 0.f;
#pragma unroll
    for (int i = 0; i < 3; i++) { v[i] = xr[tid + 256*i]; ss += v[i]*v[i]; }
#pragma unroll
    for (int off = 32; off >= 1; off >>= 1) ss += __shfl_down(ss, off);
    __shared__ float red[4];
    int lane = tid & 63, wv = tid >> 6;
    if (lane == 0) red[wv] = ss;
    __syncthreads();
    float tot = red[0] + red[1] + red[2] + red[3];
    float r = rsqrtf(tot * (1.f/(float)D_MODEL) + 1e-5f);
#pragma unroll
    for (int i = 0; i < 3; i++)
        h[(size_t)t*D_MODEL + tid + 256*i] = (bf16_t)(v[i] * r * w[tid + 256*i]);
}

// ---------------- 128x128 NT GEMM, double-buffered single-barrier K-loop ----
// C[m,n] = sum_k A[m,k]*B[n,k]. Requires M%128==0, N%128==0, K%32==0.
// LDS swizzle: row r's logical 8-elem k-chunk q stored at position q^((r>>1)&3)
// (staging loads the swizzled *global* chunk; LDS dest stays contiguous for
// global_load_lds). Prefetch for tile k+1 is issued right after the single
// per-iteration barrier, so the compiler's vmcnt(0)-before-barrier waits on a
// load that has been in flight for the whole compute phase.
// MODE 0: C(bf16) = acc
// MODE 1: C(bf16) = softplus(acc + bias[n])
// MODE 2: C(f32) = acc + resid; resid_out = resid
template<int MODE>
__global__ __launch_bounds__(256)
void gemm_nt128(const bf16_t* __restrict__ A, int lda,
                const bf16_t* __restrict__ B, int ldb,
                void* __restrict__ Cv, int ldc, int K,
                const float* __restrict__ bias,
                const float* __restrict__ resid, float* __restrict__ resid_out) {
    __shared__ __align__(16) bf16_t As[2][128*32];
    __shared__ __align__(16) bf16_t Bs[2][128*32];
    const int tid = threadIdx.x;
    const int wave = tid >> 6, lane = tid & 63;
    const int quad = lane >> 4, l16 = lane & 15;
    const int m0 = blockIdx.x * 128, n0 = blockIdx.y * 128;
    const int wr = (wave >> 1) * 64, wc = (wave & 1) * 64;

    const int s0 = tid, s1 = tid + 256;
    const int r0 = s0 >> 2, q0 = ((s0 & 3) ^ ((r0 >> 1) & 3)) << 3;
    const int r1 = s1 >> 2, q1 = ((s1 & 3) ^ ((r1 >> 1) & 3)) << 3;

    const bf16_t* Ar0 = A + (size_t)(m0 + r0)*lda + q0;
    const bf16_t* Ar1 = A + (size_t)(m0 + r1)*lda + q1;
    const bf16_t* Br0 = B + (size_t)(n0 + r0)*ldb + q0;
    const bf16_t* Br1 = B + (size_t)(n0 + r1)*ldb + q1;

    f32x4 acc[4][4] = {};
    const int nit = K >> 5;

    // prefetch tile 0 into buf 0
    g2lds16(Ar0, &As[0][wave*512]);
    g2lds16(Ar1, &As[0][wave*512 + 2048]);
    g2lds16(Br0, &Bs[0][wave*512]);
    g2lds16(Br1, &Bs[0][wave*512 + 2048]);

    for (int it = 0; it < nit; it++) {
        __syncthreads();   // waits vmcnt(0): prefetch(it) landed; prior reads drained
        if (it + 1 < nit) {
            int k = (it + 1) << 5;
            int nb = (it + 1) & 1;
            g2lds16(Ar0 + k, &As[nb][wave*512]);
            g2lds16(Ar1 + k, &As[nb][wave*512 + 2048]);
            g2lds16(Br0 + k, &Bs[nb][wave*512]);
            g2lds16(Br1 + k, &Bs[nb][wave*512 + 2048]);
        }
        const int buf = it & 1;
        bf16x8 af[4], bfr[4];
#pragma unroll
        for (int i = 0; i < 4; i++) {
            int rr = wr + i*16 + l16;
            af[i] = *(const bf16x8*)&As[buf][rr*32 + ((quad ^ ((rr >> 1) & 3)) << 3)];
        }
#pragma unroll
        for (int j = 0; j < 4; j++) {
            int rr = wc + j*16 + l16;
            bfr[j] = *(const bf16x8*)&Bs[buf][rr*32 + ((quad ^ ((rr >> 1) & 3)) << 3)];
        }
#pragma unroll
        for (int i = 0; i < 4; i++)
#pragma unroll
            for (int j = 0; j < 4; j++)
                acc[i][j] = __builtin_amdgcn_mfma_f32_16x16x32_bf16(af[i], bfr[j], acc[i][j], 0, 0, 0);
    }

#pragma unroll
    for (int i = 0; i < 4; i++) {
#pragma unroll
        for (int j = 0; j < 4; j++) {
            int n = n0 + wc + j*16 + l16;
#pragma unroll
            for (int rr = 0; rr < 4; rr++) {
                int m = m0 + wr + i*16 + quad*4 + rr;
                size_t idx = (size_t)m * ldc + n;
                float v = acc[i][j][rr];
                if (MODE == 1) {
                    float u = v + bias[n];
                    float sp = (u > 20.f) ? u : log1pf(__expf(u));
                    ((bf16_t*)Cv)[idx] = (bf16_t)sp;
                } else if (MODE == 2) {
                    float rx = resid[idx];
                    ((float*)Cv)[idx] = v + rx;
                    resid_out[idx] = rx;
                } else {
                    ((bf16_t*)Cv)[idx] = (bf16_t)v;
                }
            }
        }
    }
}

// ---------------- 64x64 NT GEMM (x_proj: N=80), swizzled LDS ----------------
__global__ __launch_bounds__(256)
void gemm_nt64(const bf16_t* __restrict__ A, int lda,
               const bf16_t* __restrict__ B, int ldb,
               bf16_t* __restrict__ C, int ldc, int N, int K) {
    __shared__ __align__(16) bf16_t As[64*32];
    __shared__ __align__(16) bf16_t Bs[64*32];
    const int tid = threadIdx.x;
    const int m0 = blockIdx.x * 64, n0 = blockIdx.y * 64;
    const int r  = tid >> 2, p8 = (tid & 3) << 3;
    const int q8 = (((tid & 3) ^ ((r >> 1) & 3)) << 3);
    const int wave = tid >> 6, lane = tid & 63;
    const int quad = lane >> 4, l16 = lane & 15;

    f32x4 acc[4] = {{0.f,0.f,0.f,0.f},{0.f,0.f,0.f,0.f},
                    {0.f,0.f,0.f,0.f},{0.f,0.f,0.f,0.f}};

    for (int k0 = 0; k0 < K; k0 += 32) {
        int gk = k0 + q8;
        uint4 va = *(const uint4*)(A + (size_t)(m0 + r) * lda + gk);
        *(uint4*)&As[r*32 + p8] = va;
        uint4 vb = {0u,0u,0u,0u};
        int nr = n0 + r;
        if (nr < N)
            vb = *(const uint4*)(B + (size_t)nr * ldb + gk);
        *(uint4*)&Bs[r*32 + p8] = vb;

        __syncthreads();
        int ra = wave*16 + l16;
        bf16x8 af = *(const bf16x8*)&As[ra*32 + ((quad ^ ((ra >> 1) & 3)) << 3)];
#pragma unroll
        for (int nt = 0; nt < 4; nt++) {
            int rb = nt*16 + l16;
            bf16x8 bfg = *(const bf16x8*)&Bs[rb*32 + ((quad ^ ((rb >> 1) & 3)) << 3)];
            acc[nt] = __builtin_amdgcn_mfma_f32_16x16x32_bf16(af, bfg, acc[nt], 0, 0, 0);
        }
        __syncthreads();
    }

#pragma unroll
    for (int nt = 0; nt < 4; nt++) {
        int n = n0 + nt*16 + l16;
        if (n >= N) continue;
#pragma unroll
        for (int rr = 0; rr < 4; rr++) {
            int m = m0 + wave*16 + quad*4 + rr;
            C[(size_t)m * ldc + n] = (bf16_t)acc[nt][rr];
        }
    }
}

// ---------------- causal depthwise conv(4) + SiLU ----------------
__global__ __launch_bounds__(256)
void conv_silu_kernel(const bf16_t* __restrict__ xz,
                      const float* __restrict__ cw,
                      const float* __restrict__ cb,
                      bf16_t* __restrict__ xc) {
    int t = blockIdx.x;
    int l = t & (SEQ - 1);
    for (int d = threadIdx.x; d < D_INNER; d += 256) {
        float acc = cb[d];
#pragma unroll
        for (int k = 0; k < 4; k++) {
            int ll = l - 3 + k;
            if (ll >= 0)
                acc += (float)xz[(size_t)(t - 3 + k) * (2*D_INNER) + d] * cw[d*4 + k];
        }
        float s = acc / (1.f + __expf(-acc));
        xc[(size_t)t * D_INNER + d] = (bf16_t)s;
    }
}

// ---------------- chunked selective scan, 16 states/thread ----------------
__global__ __launch_bounds__(256)
void scan_part1(const bf16_t* __restrict__ delta,
                const bf16_t* __restrict__ xc,
                const bf16_t* __restrict__ proj,
                const float* __restrict__ A_log,
                float* __restrict__ chunk_h, float* __restrict__ chunk_P) {
    const int tid = threadIdx.x;
    const int d = blockIdx.x * 256 + tid;
    const int c = blockIdx.y;
    const int b = blockIdx.z;
    __shared__ float Bs[LC][D_STATE];
    for (int i = tid; i < LC*D_STATE; i += 256) {
        int l = i >> 4, n = i & 15;
        size_t t = (size_t)b*SEQ + (size_t)c*LC + l;
        Bs[l][n] = (float)proj[t*XPROJ_N + DT_RANK + n];
    }
    __syncthreads();
    float Av2[D_STATE];
#pragma unroll
    for (int n = 0; n < D_STATE; n++)
        Av2[n] = -__expf(A_log[d*D_STATE + n]) * 1.44269504f;   // A[n]*log2(e)
    float s[D_STATE], P[D_STATE];
#pragma unroll
    for (int n = 0; n < D_STATE; n++) { s[n] = 0.f; P[n] = 1.f; }
    const size_t tbase = (size_t)b*SEQ + (size_t)c*LC;
    for (int l = 0; l < LC; l++) {
        size_t t = tbase + l;
        float dv  = (float)delta[t*D_INNER + d];
        float xcv = (float)xc[t*D_INNER + d];
        float dx = dv * xcv;
#pragma unroll
        for (int n = 0; n < D_STATE; n++) {
            float a = __builtin_amdgcn_exp2f(dv * Av2[n]);
            s[n] = a * s[n] + dx * Bs[l][n];
            P[n] *= a;
        }
    }
    size_t base = (((size_t)b*NCHUNK + c)*D_INNER + d)*D_STATE;
#pragma unroll
    for (int n = 0; n < D_STATE; n++) {
        chunk_h[base + n] = s[n];
        chunk_P[base + n] = P[n];
    }
}

__global__ __launch_bounds__(256)
void scan_part2(float* __restrict__ chunk_h, const float* __restrict__ chunk_P) {
    int gid = blockIdx.x * 256 + threadIdx.x;      // b*(Di*N) + d*N + n
    int b  = gid / (D_INNER * D_STATE);
    int dn = gid - b * (D_INNER * D_STATE);
    float H = 0.f;
    for (int c = 0; c < NCHUNK; c++) {
        size_t idx = ((size_t)b*NCHUNK + c)*D_INNER*D_STATE + dn;
        float S = chunk_h[idx];
        float P = chunk_P[idx];
        chunk_h[idx] = H;          // becomes the initial state for chunk c
        H = P * H + S;
    }
}

__global__ __launch_bounds__(256)
void scan_part3(const bf16_t* __restrict__ delta,
                const bf16_t* __restrict__ xc,
                const bf16_t* __restrict__ proj,
                const bf16_t* __restrict__ xz,
                const float* __restrict__ A_log,
                const float* __restrict__ Dw,
                const float* __restrict__ chunk_h,
                bf16_t* __restrict__ y) {
    const int tid = threadIdx.x;
    const int d = blockIdx.x * 256 + tid;
    const int c = blockIdx.y;
    const int b = blockIdx.z;
    __shared__ float Bs[LC][D_STATE];
    __shared__ float Cs[LC][D_STATE];
    for (int i = tid; i < LC*D_STATE; i += 256) {
        int l = i >> 4, n = i & 15;
        size_t t = (size_t)b*SEQ + (size_t)c*LC + l;
        Bs[l][n] = (float)proj[t*XPROJ_N + DT_RANK + n];
        Cs[l][n] = (float)proj[t*XPROJ_N + DT_RANK + D_STATE + n];
    }
    __syncthreads();
    float Av2[D_STATE];
#pragma unroll
    for (int n = 0; n < D_STATE; n++)
        Av2[n] = -__expf(A_log[d*D_STATE + n]) * 1.44269504f;
    const float Dv = Dw[d];
    float s[D_STATE];
    size_t base = (((size_t)b*NCHUNK + c)*D_INNER + d)*D_STATE;
#pragma unroll
    for (int n = 0; n < D_STATE; n++) s[n] = chunk_h[base + n];
    const size_t tbase = (size_t)b*SEQ + (size_t)c*LC;
    for (int l = 0; l < LC; l++) {
        size_t t = tbase + l;
        float dv  = (float)delta[t*D_INNER + d];
        float xcv = (float)xc[t*D_INNER + d];
        float dx = dv * xcv;
        float acc = 0.f;
#pragma unroll
        for (int n = 0; n < D_STATE; n++) {
            float a = __builtin_amdgcn_exp2f(dv * Av2[n]);
            s[n] = a * s[n] + dx * Bs[l][n];
            acc += s[n] * Cs[l][n];
        }
        float zf = (float)xz[t*(2*D_INNER) + D_INNER + d];
        float g = zf / (1.f + __expf(-zf));
        y[t*D_INNER + d] = (bf16_t)((acc + xcv * Dv) * g);
    }
}

extern "C" void kernel_launch(void* const* d_in, const int* in_sizes, int n_in,
                              void* d_out, int out_size, void* d_ws, size_t ws_size,
                              hipStream_t stream) {
    const float* x          = (const float*)d_in[0];
    const float* norm_w     = (const float*)d_in[1];
    const float* in_proj_w  = (const float*)d_in[2];
    const float* conv_w     = (const float*)d_in[3];
    const float* conv_b     = (const float*)d_in[4];
    const float* x_proj_w   = (const float*)d_in[5];
    const float* dt_proj_w  = (const float*)d_in[6];
    const float* dt_proj_b  = (const float*)d_in[7];
    const float* A_log      = (const float*)d_in[8];
    const float* Dw         = (const float*)d_in[9];
    const float* out_proj_w = (const float*)d_in[10];

    float* out0 = (float*)d_out;                       // x + out_proj(y)
    float* out1 = out0 + (size_t)NTOK * D_MODEL;       // residual copy

    const int n_inw = 2*D_INNER*D_MODEL;
    const int n_xpw = XPROJ_N*D_INNER;
    const int n_dtw = D_INNER*DT_K;       // padded
    const int n_opw = D_MODEL*D_INNER;
    const size_t n_chunkst = (size_t)NB*NCHUNK*D_INNER*D_STATE;

    char* ws = (char*)d_ws;
    bf16_t* w_in  = (bf16_t*)ws;  ws += (size_t)n_inw * sizeof(bf16_t);
    bf16_t* w_xp  = (bf16_t*)ws;  ws += (size_t)n_xpw * sizeof(bf16_t);
    bf16_t* w_dt  = (bf16_t*)ws;  ws += (size_t)n_dtw * sizeof(bf16_t);
    bf16_t* w_op  = (bf16_t*)ws;  ws += (size_t)n_opw * sizeof(bf16_t);
    bf16_t* h     = (bf16_t*)ws;  ws += (size_t)NTOK * D_MODEL   * sizeof(bf16_t);
    bf16_t* xz    = (bf16_t*)ws;  ws += (size_t)NTOK * 2*D_INNER * sizeof(bf16_t);
    bf16_t* xc    = (bf16_t*)ws;  ws += (size_t)NTOK * D_INNER   * sizeof(bf16_t);
    bf16_t* proj  = (bf16_t*)ws;  ws += (size_t)NTOK * XPROJ_N   * sizeof(bf16_t);
    bf16_t* delta = (bf16_t*)ws;  ws += (size_t)NTOK * D_INNER   * sizeof(bf16_t);
    bf16_t* y     = (bf16_t*)ws;  ws += (size_t)NTOK * D_INNER   * sizeof(bf16_t);
    float*  ch    = (float*)ws;   ws += n_chunkst * sizeof(float);
    float*  cP    = (float*)ws;   ws += n_chunkst * sizeof(float);

    // 0) weight fp32 -> bf16 (+ dt zero-pad to K=64)
    const int n_cvt = n_inw + n_xpw + n_opw;
    cvt3_kernel<<<(n_cvt+255)/256, 256, 0, stream>>>(
        in_proj_w, w_in, n_inw, x_proj_w, w_xp, n_xpw, out_proj_w, w_op, n_opw);
    cvt_pad_dt_kernel<<<(n_dtw+255)/256, 256, 0, stream>>>(dt_proj_w, w_dt);

    // 1) RMSNorm
    rmsnorm_kernel<<<NTOK, 256, 0, stream>>>(x, norm_w, h);
    // 2) in_proj: [4096,768] x [3072,768]^T -> xz  (dbuf 128-tile)
    gemm_nt128<0><<<dim3(NTOK/128, (2*D_INNER)/128), 256, 0, stream>>>(
        h, D_MODEL, w_in, D_MODEL, xz, 2*D_INNER, D_MODEL,
        nullptr, nullptr, nullptr);
    // 3) conv + SiLU
    conv_silu_kernel<<<NTOK, 256, 0, stream>>>(xz, conv_w, conv_b, xc);
    // 4) x_proj (N=80, 64-tile)
    gemm_nt64<<<dim3(NTOK/64, 2), 256, 0, stream>>>(
        xc, D_INNER, w_xp, D_INNER, proj, XPROJ_N, XPROJ_N, D_INNER);
    // 5) dt_proj + softplus via padded K=64 (dbuf 128-tile, MODE 1)
    gemm_nt128<1><<<dim3(NTOK/128, D_INNER/128), 256, 0, stream>>>(
        proj, XPROJ_N, w_dt, DT_K, delta, D_INNER, DT_K,
        dt_proj_b, nullptr, nullptr);
    // 6) chunked selective scan (16 states per thread, LC=32)
    scan_part1<<<dim3(D_INNER/256, NCHUNK, NB), 256, 0, stream>>>(
        delta, xc, proj, A_log, ch, cP);
    scan_part2<<<(int)((size_t)NB*D_INNER*D_STATE/256), 256, 0, stream>>>(ch, cP);
    scan_part3<<<dim3(D_INNER/256, NCHUNK, NB), 256, 0, stream>>>(
        delta, xc, proj, xz, A_log, Dw, ch, y);
    // 7) out_proj + residual add (dbuf 128-tile, MODE 2)
    gemm_nt128<2><<<dim3(NTOK/128, D_MODEL/128), 256, 0, stream>>>(
        y, D_INNER, w_op, D_INNER, out0, D_MODEL, D_INNER,
        nullptr, x, out1);
}

// Round 8
// 314.380 us; speedup vs baseline: 1.0321x; 1.0321x over previous
//
#include <hip/hip_runtime.h>
#include <cstdint>
#include <cstddef>

typedef __bf16 bf16_t;
typedef __bf16 bf16x8 __attribute__((ext_vector_type(8)));
typedef float  f32x4  __attribute__((ext_vector_type(4)));

#define D_MODEL 768
#define D_INNER 1536
#define D_STATE 16
#define DT_RANK 48
#define NB      2
#define SEQ     2048
#define NTOK    (NB*SEQ)   // 4096
#define XPROJ_N (DT_RANK + 2*D_STATE)  // 80
#define LC      32
#define NCHUNK  (SEQ/LC)   // 64
#define XP_KS   4          // x_proj split-K factor
#define XP_KC   (D_INNER/XP_KS)  // 384

// async global->LDS, 16B per lane; lds base must be wave-uniform, HW adds lane*16
typedef __attribute__((address_space(1))) void gvoid_t;
typedef __attribute__((address_space(3))) void lvoid_t;
__device__ __forceinline__ void g2lds16(const bf16_t* g, bf16_t* l) {
    __builtin_amdgcn_global_load_lds((gvoid_t*)g, (lvoid_t*)l, 16, 0, 0);
}

// ---------------- fp32 -> bf16 conversion, 4 weights in one launch ----------------
__global__ __launch_bounds__(256)
void cvt4_kernel(const float* __restrict__ s0, bf16_t* __restrict__ d0, int n0,
                 const float* __restrict__ s1, bf16_t* __restrict__ d1, int n1,
                 const float* __restrict__ s2, bf16_t* __restrict__ d2, int n2,
                 const float* __restrict__ s3, bf16_t* __restrict__ d3, int n3) {
    int i = blockIdx.x * 256 + threadIdx.x;
    if (i < n0) { d0[i] = (bf16_t)s0[i]; return; }
    i -= n0;
    if (i < n1) { d1[i] = (bf16_t)s1[i]; return; }
    i -= n1;
    if (i < n2) { d2[i] = (bf16_t)s2[i]; return; }
    i -= n2;
    if (i < n3) { d3[i] = (bf16_t)s3[i]; }
}

// ---------------- RMSNorm ----------------
__global__ __launch_bounds__(256)
void rmsnorm_kernel(const float* __restrict__ x, const float* __restrict__ w,
                    bf16_t* __restrict__ h) {
    int t = blockIdx.x;
    int tid = threadIdx.x;
    const float* xr = x + (size_t)t * D_MODEL;
    float v[3];
    float ss = 0.f;
#pragma unroll
    for (int i = 0; i < 3; i++) { v[i] = xr[tid + 256*i]; ss += v[i]*v[i]; }
#pragma unroll
    for (int off = 32; off >= 1; off >>= 1) ss += __shfl_down(ss, off);
    __shared__ float red[4];
    int lane = tid & 63, wv = tid >> 6;
    if (lane == 0) red[wv] = ss;
    __syncthreads();
    float tot = red[0] + red[1] + red[2] + red[3];
    float r = rsqrtf(tot * (1.f/(float)D_MODEL) + 1e-5f);
#pragma unroll
    for (int i = 0; i < 3; i++)
        h[(size_t)t*D_MODEL + tid + 256*i] = (bf16_t)(v[i] * r * w[tid + 256*i]);
}

// ---------------- in_proj: 128x128 NT GEMM, dbuf single-barrier, swizzled ----
__global__ __launch_bounds__(256)
void gemm_nt128(const bf16_t* __restrict__ A, int lda,
                const bf16_t* __restrict__ B, int ldb,
                bf16_t* __restrict__ C, int ldc, int K) {
    __shared__ __align__(16) bf16_t As[2][128*32];
    __shared__ __align__(16) bf16_t Bs[2][128*32];
    const int tid = threadIdx.x;
    const int wave = tid >> 6, lane = tid & 63;
    const int quad = lane >> 4, l16 = lane & 15;
    const int m0 = blockIdx.x * 128, n0 = blockIdx.y * 128;
    const int wr = (wave >> 1) * 64, wc = (wave & 1) * 64;

    const int s0 = tid, s1 = tid + 256;
    const int r0 = s0 >> 2, q0 = ((s0 & 3) ^ ((r0 >> 1) & 3)) << 3;
    const int r1 = s1 >> 2, q1 = ((s1 & 3) ^ ((r1 >> 1) & 3)) << 3;

    const bf16_t* Ar0 = A + (size_t)(m0 + r0)*lda + q0;
    const bf16_t* Ar1 = A + (size_t)(m0 + r1)*lda + q1;
    const bf16_t* Br0 = B + (size_t)(n0 + r0)*ldb + q0;
    const bf16_t* Br1 = B + (size_t)(n0 + r1)*ldb + q1;

    f32x4 acc[4][4] = {};
    const int nit = K >> 5;

    g2lds16(Ar0, &As[0][wave*512]);
    g2lds16(Ar1, &As[0][wave*512 + 2048]);
    g2lds16(Br0, &Bs[0][wave*512]);
    g2lds16(Br1, &Bs[0][wave*512 + 2048]);

    for (int it = 0; it < nit; it++) {
        __syncthreads();
        if (it + 1 < nit) {
            int k = (it + 1) << 5;
            int nb = (it + 1) & 1;
            g2lds16(Ar0 + k, &As[nb][wave*512]);
            g2lds16(Ar1 + k, &As[nb][wave*512 + 2048]);
            g2lds16(Br0 + k, &Bs[nb][wave*512]);
            g2lds16(Br1 + k, &Bs[nb][wave*512 + 2048]);
        }
        const int buf = it & 1;
        bf16x8 af[4], bfr[4];
#pragma unroll
        for (int i = 0; i < 4; i++) {
            int rr = wr + i*16 + l16;
            af[i] = *(const bf16x8*)&As[buf][rr*32 + ((quad ^ ((rr >> 1) & 3)) << 3)];
        }
#pragma unroll
        for (int j = 0; j < 4; j++) {
            int rr = wc + j*16 + l16;
            bfr[j] = *(const bf16x8*)&Bs[buf][rr*32 + ((quad ^ ((rr >> 1) & 3)) << 3)];
        }
#pragma unroll
        for (int i = 0; i < 4; i++)
#pragma unroll
            for (int j = 0; j < 4; j++)
                acc[i][j] = __builtin_amdgcn_mfma_f32_16x16x32_bf16(af[i], bfr[j], acc[i][j], 0, 0, 0);
    }

#pragma unroll
    for (int i = 0; i < 4; i++)
#pragma unroll
        for (int j = 0; j < 4; j++) {
            int n = n0 + wc + j*16 + l16;
#pragma unroll
            for (int rr = 0; rr < 4; rr++) {
                int m = m0 + wr + i*16 + quad*4 + rr;
                C[(size_t)m * ldc + n] = (bf16_t)acc[i][j][rr];
            }
        }
}

// ---------------- out_proj: 128x64 NT GEMM, dbuf, + residual epilogue -------
// C(f32)[m,n] = acc + resid; resid_out = resid. A=[4096,1536], B=[768,1536].
__global__ __launch_bounds__(256)
void gemm_op(const bf16_t* __restrict__ A, const bf16_t* __restrict__ B,
             float* __restrict__ C, const float* __restrict__ resid,
             float* __restrict__ resid_out) {
    __shared__ __align__(16) bf16_t As[2][128*32];
    __shared__ __align__(16) bf16_t Bs[2][64*32];
    const int tid = threadIdx.x;
    const int wave = tid >> 6, lane = tid & 63;
    const int quad = lane >> 4, l16 = lane & 15;
    const int m0 = blockIdx.x * 128, n0 = blockIdx.y * 64;
    const int wr = (wave >> 1) * 64, wc = (wave & 1) * 32;

    const int s0 = tid, s1 = tid + 256;
    const int r0 = s0 >> 2, q0 = ((s0 & 3) ^ ((r0 >> 1) & 3)) << 3;
    const int r1 = s1 >> 2, q1 = ((s1 & 3) ^ ((r1 >> 1) & 3)) << 3;
    const int rB = tid >> 2, qB = (((tid & 3) ^ ((rB >> 1) & 3)) << 3);

    const bf16_t* Ar0 = A + (size_t)(m0 + r0)*D_INNER + q0;
    const bf16_t* Ar1 = A + (size_t)(m0 + r1)*D_INNER + q1;
    const bf16_t* Brp = B + (size_t)(n0 + rB)*D_INNER + qB;

    f32x4 acc[4][2] = {};
    const int nit = D_INNER >> 5;   // 48

    g2lds16(Ar0, &As[0][wave*512]);
    g2lds16(Ar1, &As[0][wave*512 + 2048]);
    g2lds16(Brp, &Bs[0][wave*512]);

    for (int it = 0; it < nit; it++) {
        __syncthreads();
        if (it + 1 < nit) {
            int k = (it + 1) << 5;
            int nb = (it + 1) & 1;
            g2lds16(Ar0 + k, &As[nb][wave*512]);
            g2lds16(Ar1 + k, &As[nb][wave*512 + 2048]);
            g2lds16(Brp + k, &Bs[nb][wave*512]);
        }
        const int buf = it & 1;
        bf16x8 af[4], bfr[2];
#pragma unroll
        for (int i = 0; i < 4; i++) {
            int rr = wr + i*16 + l16;
            af[i] = *(const bf16x8*)&As[buf][rr*32 + ((quad ^ ((rr >> 1) & 3)) << 3)];
        }
#pragma unroll
        for (int j = 0; j < 2; j++) {
            int rr = wc + j*16 + l16;
            bfr[j] = *(const bf16x8*)&Bs[buf][rr*32 + ((quad ^ ((rr >> 1) & 3)) << 3)];
        }
#pragma unroll
        for (int i = 0; i < 4; i++)
#pragma unroll
            for (int j = 0; j < 2; j++)
                acc[i][j] = __builtin_amdgcn_mfma_f32_16x16x32_bf16(af[i], bfr[j], acc[i][j], 0, 0, 0);
    }

#pragma unroll
    for (int i = 0; i < 4; i++)
#pragma unroll
        for (int j = 0; j < 2; j++) {
            int n = n0 + wc + j*16 + l16;
#pragma unroll
            for (int rr = 0; rr < 4; rr++) {
                int m = m0 + wr + i*16 + quad*4 + rr;
                size_t idx = (size_t)m * D_MODEL + n;
                float rx = resid[idx];
                C[idx] = acc[i][j][rr] + rx;
                resid_out[idx] = rx;
            }
        }
}

// ---------------- x_proj: 64x64 tile, split-K x4, fp32 partials -------------
__global__ __launch_bounds__(256)
void gemm_xp(const bf16_t* __restrict__ A, const bf16_t* __restrict__ B,
             float* __restrict__ pbuf) {
    __shared__ __align__(16) bf16_t As[64*32];
    __shared__ __align__(16) bf16_t Bs[64*32];
    const int tid = threadIdx.x;
    const int m0 = blockIdx.x * 64, n0 = blockIdx.y * 64, kbase = blockIdx.z * XP_KC;
    const int r  = tid >> 2, p8 = (tid & 3) << 3;
    const int q8 = (((tid & 3) ^ ((r >> 1) & 3)) << 3);
    const int wave = tid >> 6, lane = tid & 63;
    const int quad = lane >> 4, l16 = lane & 15;

    f32x4 acc[4] = {{0.f,0.f,0.f,0.f},{0.f,0.f,0.f,0.f},
                    {0.f,0.f,0.f,0.f},{0.f,0.f,0.f,0.f}};

    for (int k0 = 0; k0 < XP_KC; k0 += 32) {
        int gk = kbase + k0 + q8;
        uint4 va = *(const uint4*)(A + (size_t)(m0 + r) * D_INNER + gk);
        *(uint4*)&As[r*32 + p8] = va;
        uint4 vb = {0u,0u,0u,0u};
        int nr = n0 + r;
        if (nr < XPROJ_N)
            vb = *(const uint4*)(B + (size_t)nr * D_INNER + gk);
        *(uint4*)&Bs[r*32 + p8] = vb;

        __syncthreads();
        int ra = wave*16 + l16;
        bf16x8 af = *(const bf16x8*)&As[ra*32 + ((quad ^ ((ra >> 1) & 3)) << 3)];
#pragma unroll
        for (int nt = 0; nt < 4; nt++) {
            int rb = nt*16 + l16;
            bf16x8 bfg = *(const bf16x8*)&Bs[rb*32 + ((quad ^ ((rb >> 1) & 3)) << 3)];
            acc[nt] = __builtin_amdgcn_mfma_f32_16x16x32_bf16(af, bfg, acc[nt], 0, 0, 0);
        }
        __syncthreads();
    }

#pragma unroll
    for (int nt = 0; nt < 4; nt++) {
        int n = n0 + nt*16 + l16;
        if (n >= XPROJ_N) continue;
#pragma unroll
        for (int rr = 0; rr < 4; rr++) {
            int m = m0 + wave*16 + quad*4 + rr;
            pbuf[((size_t)blockIdx.z * NTOK + m) * XPROJ_N + n] = acc[nt][rr];
        }
    }
}

__global__ __launch_bounds__(256)
void xp_reduce_kernel(const float* __restrict__ pbuf, bf16_t* __restrict__ proj) {
    int i = blockIdx.x * 256 + threadIdx.x;
    if (i >= NTOK * XPROJ_N) return;
    float s = 0.f;
#pragma unroll
    for (int z = 0; z < XP_KS; z++)
        s += pbuf[(size_t)z * NTOK * XPROJ_N + i];
    proj[i] = (bf16_t)s;
}

// ---------------- dt_proj: 64x64 tile, K=48, softplus+bias epilogue ---------
__global__ __launch_bounds__(256)
void gemm_dt(const bf16_t* __restrict__ A, const bf16_t* __restrict__ B,
             bf16_t* __restrict__ C, const float* __restrict__ bias) {
    __shared__ __align__(16) bf16_t As[64*32];
    __shared__ __align__(16) bf16_t Bs[64*32];
    const int tid = threadIdx.x;
    const int m0 = blockIdx.x * 64, n0 = blockIdx.y * 64;
    const int r  = tid >> 2, p8 = (tid & 3) << 3;
    const int q8 = (((tid & 3) ^ ((r >> 1) & 3)) << 3);
    const int wave = tid >> 6, lane = tid & 63;
    const int quad = lane >> 4, l16 = lane & 15;

    f32x4 acc[4] = {{0.f,0.f,0.f,0.f},{0.f,0.f,0.f,0.f},
                    {0.f,0.f,0.f,0.f},{0.f,0.f,0.f,0.f}};

    for (int k0 = 0; k0 < DT_RANK; k0 += 32) {
        int gk = k0 + q8;
        uint4 va = {0u,0u,0u,0u};
        if (gk + 8 <= DT_RANK)
            va = *(const uint4*)(A + (size_t)(m0 + r) * XPROJ_N + gk);
        *(uint4*)&As[r*32 + p8] = va;
        uint4 vb = {0u,0u,0u,0u};
        if (gk + 8 <= DT_RANK)
            vb = *(const uint4*)(B + (size_t)(n0 + r) * DT_RANK + gk);
        *(uint4*)&Bs[r*32 + p8] = vb;

        __syncthreads();
        int ra = wave*16 + l16;
        bf16x8 af = *(const bf16x8*)&As[ra*32 + ((quad ^ ((ra >> 1) & 3)) << 3)];
#pragma unroll
        for (int nt = 0; nt < 4; nt++) {
            int rb = nt*16 + l16;
            bf16x8 bfg = *(const bf16x8*)&Bs[rb*32 + ((quad ^ ((rb >> 1) & 3)) << 3)];
            acc[nt] = __builtin_amdgcn_mfma_f32_16x16x32_bf16(af, bfg, acc[nt], 0, 0, 0);
        }
        __syncthreads();
    }

#pragma unroll
    for (int nt = 0; nt < 4; nt++) {
        int n = n0 + nt*16 + l16;
#pragma unroll
        for (int rr = 0; rr < 4; rr++) {
            int m = m0 + wave*16 + quad*4 + rr;
            float u = acc[nt][rr] + bias[n];
            float sp = (u > 20.f) ? u : log1pf(__expf(u));
            C[(size_t)m * D_INNER + n] = (bf16_t)sp;
        }
    }
}

// ---------------- causal depthwise conv(4) + SiLU, 2 channels/thread --------
__global__ __launch_bounds__(256)
void conv_silu_kernel(const bf16_t* __restrict__ xz,
                      const float* __restrict__ cw,
                      const float* __restrict__ cb,
                      bf16_t* __restrict__ xc) {
    int t = blockIdx.x;
    int l = t & (SEQ - 1);
    for (int dd = threadIdx.x; dd < D_INNER/2; dd += 256) {
        int d = dd * 2;
        float a0 = cb[d], a1 = cb[d+1];
#pragma unroll
        for (int k = 0; k < 4; k++) {
            int ll = l - 3 + k;
            if (ll >= 0) {
                ushort2 u = *(const ushort2*)&xz[(size_t)(t - 3 + k) * (2*D_INNER) + d];
                float x0 = __uint_as_float((unsigned)u.x << 16);
                float x1 = __uint_as_float((unsigned)u.y << 16);
                a0 += x0 * cw[d*4 + k];
                a1 += x1 * cw[(d+1)*4 + k];
            }
        }
        float s0 = a0 / (1.f + __expf(-a0));
        float s1 = a1 / (1.f + __expf(-a1));
        xc[(size_t)t * D_INNER + d]     = (bf16_t)s0;
        xc[(size_t)t * D_INNER + d + 1] = (bf16_t)s1;
    }
}

// ---------------- chunked selective scan, 16 states/thread ----------------
__global__ __launch_bounds__(256)
void scan_part1(const bf16_t* __restrict__ delta,
                const bf16_t* __restrict__ xc,
                const bf16_t* __restrict__ proj,
                const float* __restrict__ A_log,
                float* __restrict__ chunk_h, float* __restrict__ chunk_P) {
    const int tid = threadIdx.x;
    const int d = blockIdx.x * 256 + tid;
    const int c = blockIdx.y;
    const int b = blockIdx.z;
    __shared__ float Bs[LC][D_STATE];
    for (int i = tid; i < LC*D_STATE; i += 256) {
        int l = i >> 4, n = i & 15;
        size_t t = (size_t)b*SEQ + (size_t)c*LC + l;
        Bs[l][n] = (float)proj[t*XPROJ_N + DT_RANK + n];
    }
    __syncthreads();
    float Av2[D_STATE];
#pragma unroll
    for (int n = 0; n < D_STATE; n++)
        Av2[n] = -__expf(A_log[d*D_STATE + n]) * 1.44269504f;   // A[n]*log2(e)
    float s[D_STATE];
#pragma unroll
    for (int n = 0; n < D_STATE; n++) s[n] = 0.f;
    float sdv = 0.f;
    const size_t tbase = (size_t)b*SEQ + (size_t)c*LC;
    for (int l = 0; l < LC; l++) {
        size_t t = tbase + l;
        float dv  = (float)delta[t*D_INNER + d];
        float xcv = (float)xc[t*D_INNER + d];
        float dx = dv * xcv;
        sdv += dv;
#pragma unroll
        for (int n = 0; n < D_STATE; n++) {
            float a = __builtin_amdgcn_exp2f(dv * Av2[n]);
            s[n] = a * s[n] + dx * Bs[l][n];
        }
    }
    size_t base = (((size_t)b*NCHUNK + c)*D_INNER + d)*D_STATE;
#pragma unroll
    for (int n = 0; n < D_STATE; n++) {
        chunk_h[base + n] = s[n];
        chunk_P[base + n] = __builtin_amdgcn_exp2f(Av2[n] * sdv);  // = prod a
    }
}

__global__ __launch_bounds__(256)
void scan_part2(float* __restrict__ chunk_h, const float* __restrict__ chunk_P) {
    int gid = blockIdx.x * 256 + threadIdx.x;      // b*(Di*N) + d*N + n
    int b  = gid / (D_INNER * D_STATE);
    int dn = gid - b * (D_INNER * D_STATE);
    float H = 0.f;
    for (int c = 0; c < NCHUNK; c++) {
        size_t idx = ((size_t)b*NCHUNK + c)*D_INNER*D_STATE + dn;
        float S = chunk_h[idx];
        float P = chunk_P[idx];
        chunk_h[idx] = H;          // becomes the initial state for chunk c
        H = P * H + S;
    }
}

__global__ __launch_bounds__(256)
void scan_part3(const bf16_t* __restrict__ delta,
                const bf16_t* __restrict__ xc,
                const bf16_t* __restrict__ proj,
                const bf16_t* __restrict__ xz,
                const float* __restrict__ A_log,
                const float* __restrict__ Dw,
                const float* __restrict__ chunk_h,
                bf16_t* __restrict__ y) {
    const int tid = threadIdx.x;
    const int d = blockIdx.x * 256 + tid;
    const int c = blockIdx.y;
    const int b = blockIdx.z;
    __shared__ float Bs[LC][D_STATE];
    __shared__ float Cs[LC][D_STATE];
    for (int i = tid; i < LC*D_STATE; i += 256) {
        int l = i >> 4, n = i & 15;
        size_t t = (size_t)b*SEQ + (size_t)c*LC + l;
        Bs[l][n] = (float)proj[t*XPROJ_N + DT_RANK + n];
        Cs[l][n] = (float)proj[t*XPROJ_N + DT_RANK + D_STATE + n];
    }
    __syncthreads();
    float Av2[D_STATE];
#pragma unroll
    for (int n = 0; n < D_STATE; n++)
        Av2[n] = -__expf(A_log[d*D_STATE + n]) * 1.44269504f;
    const float Dv = Dw[d];
    float s[D_STATE];
    size_t base = (((size_t)b*NCHUNK + c)*D_INNER + d)*D_STATE;
#pragma unroll
    for (int n = 0; n < D_STATE; n++) s[n] = chunk_h[base + n];
    const size_t tbase = (size_t)b*SEQ + (size_t)c*LC;
    for (int l = 0; l < LC; l++) {
        size_t t = tbase + l;
        float dv  = (float)delta[t*D_INNER + d];
        float xcv = (float)xc[t*D_INNER + d];
        float dx = dv * xcv;
        float acc = 0.f;
#pragma unroll
        for (int n = 0; n < D_STATE; n++) {
            float a = __builtin_amdgcn_exp2f(dv * Av2[n]);
            s[n] = a * s[n] + dx * Bs[l][n];
            acc += s[n] * Cs[l][n];
        }
        float zf = (float)xz[t*(2*D_INNER) + D_INNER + d];
        float g = zf / (1.f + __expf(-zf));
        y[t*D_INNER + d] = (bf16_t)((acc + xcv * Dv) * g);
    }
}

extern "C" void kernel_launch(void* const* d_in, const int* in_sizes, int n_in,
                              void* d_out, int out_size, void* d_ws, size_t ws_size,
                              hipStream_t stream) {
    const float* x          = (const float*)d_in[0];
    const float* norm_w     = (const float*)d_in[1];
    const float* in_proj_w  = (const float*)d_in[2];
    const float* conv_w     = (const float*)d_in[3];
    const float* conv_b     = (const float*)d_in[4];
    const float* x_proj_w   = (const float*)d_in[5];
    const float* dt_proj_w  = (const float*)d_in[6];
    const float* dt_proj_b  = (const float*)d_in[7];
    const float* A_log      = (const float*)d_in[8];
    const float* Dw         = (const float*)d_in[9];
    const float* out_proj_w = (const float*)d_in[10];

    float* out0 = (float*)d_out;                       // x + out_proj(y)
    float* out1 = out0 + (size_t)NTOK * D_MODEL;       // residual copy

    const int n_inw = 2*D_INNER*D_MODEL;
    const int n_xpw = XPROJ_N*D_INNER;
    const int n_dtw = D_INNER*DT_RANK;
    const int n_opw = D_MODEL*D_INNER;
    const size_t n_chunkst = (size_t)NB*NCHUNK*D_INNER*D_STATE;

    char* ws = (char*)d_ws;
    bf16_t* w_in  = (bf16_t*)ws;  ws += (size_t)n_inw * sizeof(bf16_t);
    bf16_t* w_xp  = (bf16_t*)ws;  ws += (size_t)n_xpw * sizeof(bf16_t);
    bf16_t* w_dt  = (bf16_t*)ws;  ws += (size_t)n_dtw * sizeof(bf16_t);
    bf16_t* w_op  = (bf16_t*)ws;  ws += (size_t)n_opw * sizeof(bf16_t);
    bf16_t* h     = (bf16_t*)ws;  ws += (size_t)NTOK * D_MODEL   * sizeof(bf16_t);
    bf16_t* xz    = (bf16_t*)ws;  ws += (size_t)NTOK * 2*D_INNER * sizeof(bf16_t);
    bf16_t* xc    = (bf16_t*)ws;  ws += (size_t)NTOK * D_INNER   * sizeof(bf16_t);
    bf16_t* proj  = (bf16_t*)ws;  ws += (size_t)NTOK * XPROJ_N   * sizeof(bf16_t);
    bf16_t* delta = (bf16_t*)ws;  ws += (size_t)NTOK * D_INNER   * sizeof(bf16_t);
    bf16_t* y     = (bf16_t*)ws;  ws += (size_t)NTOK * D_INNER   * sizeof(bf16_t);
    float*  ch    = (float*)ws;   ws += n_chunkst * sizeof(float);
    float*  cP    = (float*)ws;   ws += n_chunkst * sizeof(float);
    float*  xppart= (float*)ws;   ws += (size_t)XP_KS * NTOK * XPROJ_N * sizeof(float);

    // 0) weight fp32 -> bf16
    const int n_cvt = n_inw + n_xpw + n_dtw + n_opw;
    cvt4_kernel<<<(n_cvt+255)/256, 256, 0, stream>>>(
        in_proj_w, w_in, n_inw, x_proj_w, w_xp, n_xpw,
        dt_proj_w, w_dt, n_dtw, out_proj_w, w_op, n_opw);

    // 1) RMSNorm
    rmsnorm_kernel<<<NTOK, 256, 0, stream>>>(x, norm_w, h);
    // 2) in_proj (dbuf 128-tile)
    gemm_nt128<<<dim3(NTOK/128, (2*D_INNER)/128), 256, 0, stream>>>(
        h, D_MODEL, w_in, D_MODEL, xz, 2*D_INNER, D_MODEL);
    // 3) conv + SiLU
    conv_silu_kernel<<<NTOK, 256, 0, stream>>>(xz, conv_w, conv_b, xc);
    // 4) x_proj split-K x4 + reduce
    gemm_xp<<<dim3(NTOK/64, 2, XP_KS), 256, 0, stream>>>(xc, w_xp, xppart);
    xp_reduce_kernel<<<(NTOK*XPROJ_N + 255)/256, 256, 0, stream>>>(xppart, proj);
    // 5) dt_proj + softplus (64-tile, K=48)
    gemm_dt<<<dim3(NTOK/64, D_INNER/64), 256, 0, stream>>>(proj, w_dt, delta, dt_proj_b);
    // 6) chunked selective scan
    scan_part1<<<dim3(D_INNER/256, NCHUNK, NB), 256, 0, stream>>>(
        delta, xc, proj, A_log, ch, cP);
    scan_part2<<<(int)((size_t)NB*D_INNER*D_STATE/256), 256, 0, stream>>>(ch, cP);
    scan_part3<<<dim3(D_INNER/256, NCHUNK, NB), 256, 0, stream>>>(
        delta, xc, proj, xz, A_log, Dw, ch, y);
    // 7) out_proj 128x64 dbuf + residual epilogue
    gemm_op<<<dim3(NTOK/128, D_MODEL/64), 256, 0, stream>>>(
        y, w_op, out0, x, out1);
}

// Round 9
// 291.350 us; speedup vs baseline: 1.1137x; 1.0790x over previous
//
#include <hip/hip_runtime.h>
#include <cstdint>
#include <cstddef>

typedef __bf16 bf16_t;
typedef __bf16 bf16x8 __attribute__((ext_vector_type(8)));
typedef float  f32x4  __attribute__((ext_vector_type(4)));

#define D_MODEL 768
#define D_INNER 1536
#define D_STATE 16
#define DT_RANK 48
#define NB      2
#define SEQ     2048
#define NTOK    (NB*SEQ)   // 4096
#define XPROJ_N (DT_RANK + 2*D_STATE)  // 80
#define LC      32
#define NCHUNK  (SEQ/LC)   // 64
#define XP_KS   4          // x_proj split-K factor
#define XP_KC   (D_INNER/XP_KS)  // 384

#define N_INW (2*D_INNER*D_MODEL)   // 2359296
#define N_XPW (XPROJ_N*D_INNER)     // 122880
#define N_DTW (D_INNER*DT_RANK)     // 73728
#define N_OPW (D_MODEL*D_INNER)     // 1179648
#define N_CVT (N_INW+N_XPW+N_DTW+N_OPW)       // 3735552
#define CVT_BLOCKS (N_CVT/1024)               // 3648 (256 thr x 4 elem)

// async global->LDS, 16B per lane; lds base must be wave-uniform, HW adds lane*16
typedef __attribute__((address_space(1))) void gvoid_t;
typedef __attribute__((address_space(3))) void lvoid_t;
__device__ __forceinline__ void g2lds16(const bf16_t* g, bf16_t* l) {
    __builtin_amdgcn_global_load_lds((gvoid_t*)g, (lvoid_t*)l, 16, 0, 0);
}

// ---------------- prep: weight fp32->bf16 (vectorized) + RMSNorm ------------
__global__ __launch_bounds__(256)
void prep_kernel(const float* __restrict__ in_proj_w, bf16_t* __restrict__ w_in,
                 const float* __restrict__ x_proj_w,  bf16_t* __restrict__ w_xp,
                 const float* __restrict__ dt_proj_w, bf16_t* __restrict__ w_dt,
                 const float* __restrict__ out_proj_w,bf16_t* __restrict__ w_op,
                 const float* __restrict__ x, const float* __restrict__ norm_w,
                 bf16_t* __restrict__ h) {
    const int blk = blockIdx.x;
    const int tid = threadIdx.x;
    if (blk < CVT_BLOCKS) {
        int off = (blk * 256 + tid) * 4;
        const float* s; bf16_t* d;
        if (off < N_INW) { s = in_proj_w + off; d = w_in + off; }
        else if ((off -= N_INW) < N_XPW) { s = x_proj_w + off; d = w_xp + off; }
        else if ((off -= N_XPW) < N_DTW) { s = dt_proj_w + off; d = w_dt + off; }
        else { off -= N_DTW; s = out_proj_w + off; d = w_op + off; }
        float4 v = *(const float4*)s;
        d[0] = (bf16_t)v.x; d[1] = (bf16_t)v.y;
        d[2] = (bf16_t)v.z; d[3] = (bf16_t)v.w;
        return;
    }
    // RMSNorm: one block per token
    int t = blk - CVT_BLOCKS;
    const float* xr = x + (size_t)t * D_MODEL;
    float v[3];
    float ss = 0.f;
#pragma unroll
    for (int i = 0; i < 3; i++) { v[i] = xr[tid + 256*i]; ss += v[i]*v[i]; }
#pragma unroll
    for (int off = 32; off >= 1; off >>= 1) ss += __shfl_down(ss, off);
    __shared__ float red[4];
    int lane = tid & 63, wv = tid >> 6;
    if (lane == 0) red[wv] = ss;
    __syncthreads();
    float tot = red[0] + red[1] + red[2] + red[3];
    float r = rsqrtf(tot * (1.f/(float)D_MODEL) + 1e-5f);
#pragma unroll
    for (int i = 0; i < 3; i++)
        h[(size_t)t*D_MODEL + tid + 256*i] = (bf16_t)(v[i] * r * norm_w[tid + 256*i]);
}

// ---------------- in_proj: 128x128 NT GEMM, dbuf single-barrier, swizzled ----
__global__ __launch_bounds__(256)
void gemm_nt128(const bf16_t* __restrict__ A, int lda,
                const bf16_t* __restrict__ B, int ldb,
                bf16_t* __restrict__ C, int ldc, int K) {
    __shared__ __align__(16) bf16_t As[2][128*32];
    __shared__ __align__(16) bf16_t Bs[2][128*32];
    const int tid = threadIdx.x;
    const int wave = tid >> 6, lane = tid & 63;
    const int quad = lane >> 4, l16 = lane & 15;
    const int m0 = blockIdx.x * 128, n0 = blockIdx.y * 128;
    const int wr = (wave >> 1) * 64, wc = (wave & 1) * 64;

    const int s0 = tid, s1 = tid + 256;
    const int r0 = s0 >> 2, q0 = ((s0 & 3) ^ ((r0 >> 1) & 3)) << 3;
    const int r1 = s1 >> 2, q1 = ((s1 & 3) ^ ((r1 >> 1) & 3)) << 3;

    const bf16_t* Ar0 = A + (size_t)(m0 + r0)*lda + q0;
    const bf16_t* Ar1 = A + (size_t)(m0 + r1)*lda + q1;
    const bf16_t* Br0 = B + (size_t)(n0 + r0)*ldb + q0;
    const bf16_t* Br1 = B + (size_t)(n0 + r1)*ldb + q1;

    f32x4 acc[4][4] = {};
    const int nit = K >> 5;

    g2lds16(Ar0, &As[0][wave*512]);
    g2lds16(Ar1, &As[0][wave*512 + 2048]);
    g2lds16(Br0, &Bs[0][wave*512]);
    g2lds16(Br1, &Bs[0][wave*512 + 2048]);

    for (int it = 0; it < nit; it++) {
        __syncthreads();
        if (it + 1 < nit) {
            int k = (it + 1) << 5;
            int nb = (it + 1) & 1;
            g2lds16(Ar0 + k, &As[nb][wave*512]);
            g2lds16(Ar1 + k, &As[nb][wave*512 + 2048]);
            g2lds16(Br0 + k, &Bs[nb][wave*512]);
            g2lds16(Br1 + k, &Bs[nb][wave*512 + 2048]);
        }
        const int buf = it & 1;
        bf16x8 af[4], bfr[4];
#pragma unroll
        for (int i = 0; i < 4; i++) {
            int rr = wr + i*16 + l16;
            af[i] = *(const bf16x8*)&As[buf][rr*32 + ((quad ^ ((rr >> 1) & 3)) << 3)];
        }
#pragma unroll
        for (int j = 0; j < 4; j++) {
            int rr = wc + j*16 + l16;
            bfr[j] = *(const bf16x8*)&Bs[buf][rr*32 + ((quad ^ ((rr >> 1) & 3)) << 3)];
        }
#pragma unroll
        for (int i = 0; i < 4; i++)
#pragma unroll
            for (int j = 0; j < 4; j++)
                acc[i][j] = __builtin_amdgcn_mfma_f32_16x16x32_bf16(af[i], bfr[j], acc[i][j], 0, 0, 0);
    }

#pragma unroll
    for (int i = 0; i < 4; i++)
#pragma unroll
        for (int j = 0; j < 4; j++) {
            int n = n0 + wc + j*16 + l16;
#pragma unroll
            for (int rr = 0; rr < 4; rr++) {
                int m = m0 + wr + i*16 + quad*4 + rr;
                C[(size_t)m * ldc + n] = (bf16_t)acc[i][j][rr];
            }
        }
}

// ---------------- out_proj: 128x64 NT GEMM, dbuf, + residual epilogue -------
__global__ __launch_bounds__(256)
void gemm_op(const bf16_t* __restrict__ A, const bf16_t* __restrict__ B,
             float* __restrict__ C, const float* __restrict__ resid,
             float* __restrict__ resid_out) {
    __shared__ __align__(16) bf16_t As[2][128*32];
    __shared__ __align__(16) bf16_t Bs[2][64*32];
    const int tid = threadIdx.x;
    const int wave = tid >> 6, lane = tid & 63;
    const int quad = lane >> 4, l16 = lane & 15;
    const int m0 = blockIdx.x * 128, n0 = blockIdx.y * 64;
    const int wr = (wave >> 1) * 64, wc = (wave & 1) * 32;

    const int s0 = tid, s1 = tid + 256;
    const int r0 = s0 >> 2, q0 = ((s0 & 3) ^ ((r0 >> 1) & 3)) << 3;
    const int r1 = s1 >> 2, q1 = ((s1 & 3) ^ ((r1 >> 1) & 3)) << 3;
    const int rB = tid >> 2, qB = (((tid & 3) ^ ((rB >> 1) & 3)) << 3);

    const bf16_t* Ar0 = A + (size_t)(m0 + r0)*D_INNER + q0;
    const bf16_t* Ar1 = A + (size_t)(m0 + r1)*D_INNER + q1;
    const bf16_t* Brp = B + (size_t)(n0 + rB)*D_INNER + qB;

    f32x4 acc[4][2] = {};
    const int nit = D_INNER >> 5;   // 48

    g2lds16(Ar0, &As[0][wave*512]);
    g2lds16(Ar1, &As[0][wave*512 + 2048]);
    g2lds16(Brp, &Bs[0][wave*512]);

    for (int it = 0; it < nit; it++) {
        __syncthreads();
        if (it + 1 < nit) {
            int k = (it + 1) << 5;
            int nb = (it + 1) & 1;
            g2lds16(Ar0 + k, &As[nb][wave*512]);
            g2lds16(Ar1 + k, &As[nb][wave*512 + 2048]);
            g2lds16(Brp + k, &Bs[nb][wave*512]);
        }
        const int buf = it & 1;
        bf16x8 af[4], bfr[2];
#pragma unroll
        for (int i = 0; i < 4; i++) {
            int rr = wr + i*16 + l16;
            af[i] = *(const bf16x8*)&As[buf][rr*32 + ((quad ^ ((rr >> 1) & 3)) << 3)];
        }
#pragma unroll
        for (int j = 0; j < 2; j++) {
            int rr = wc + j*16 + l16;
            bfr[j] = *(const bf16x8*)&Bs[buf][rr*32 + ((quad ^ ((rr >> 1) & 3)) << 3)];
        }
#pragma unroll
        for (int i = 0; i < 4; i++)
#pragma unroll
            for (int j = 0; j < 2; j++)
                acc[i][j] = __builtin_amdgcn_mfma_f32_16x16x32_bf16(af[i], bfr[j], acc[i][j], 0, 0, 0);
    }

#pragma unroll
    for (int i = 0; i < 4; i++)
#pragma unroll
        for (int j = 0; j < 2; j++) {
            int n = n0 + wc + j*16 + l16;
#pragma unroll
            for (int rr = 0; rr < 4; rr++) {
                int m = m0 + wr + i*16 + quad*4 + rr;
                size_t idx = (size_t)m * D_MODEL + n;
                float rx = resid[idx];
                C[idx] = acc[i][j][rr] + rx;
                resid_out[idx] = rx;
            }
        }
}

// ---------------- x_proj: 64x64 tile, split-K x4, fp32 partials -------------
__global__ __launch_bounds__(256)
void gemm_xp(const bf16_t* __restrict__ A, const bf16_t* __restrict__ B,
             float* __restrict__ pbuf) {
    __shared__ __align__(16) bf16_t As[64*32];
    __shared__ __align__(16) bf16_t Bs[64*32];
    const int tid = threadIdx.x;
    const int m0 = blockIdx.x * 64, n0 = blockIdx.y * 64, kbase = blockIdx.z * XP_KC;
    const int r  = tid >> 2, p8 = (tid & 3) << 3;
    const int q8 = (((tid & 3) ^ ((r >> 1) & 3)) << 3);
    const int wave = tid >> 6, lane = tid & 63;
    const int quad = lane >> 4, l16 = lane & 15;

    f32x4 acc[4] = {{0.f,0.f,0.f,0.f},{0.f,0.f,0.f,0.f},
                    {0.f,0.f,0.f,0.f},{0.f,0.f,0.f,0.f}};

    for (int k0 = 0; k0 < XP_KC; k0 += 32) {
        int gk = kbase + k0 + q8;
        uint4 va = *(const uint4*)(A + (size_t)(m0 + r) * D_INNER + gk);
        *(uint4*)&As[r*32 + p8] = va;
        uint4 vb = {0u,0u,0u,0u};
        int nr = n0 + r;
        if (nr < XPROJ_N)
            vb = *(const uint4*)(B + (size_t)nr * D_INNER + gk);
        *(uint4*)&Bs[r*32 + p8] = vb;

        __syncthreads();
        int ra = wave*16 + l16;
        bf16x8 af = *(const bf16x8*)&As[ra*32 + ((quad ^ ((ra >> 1) & 3)) << 3)];
#pragma unroll
        for (int nt = 0; nt < 4; nt++) {
            int rb = nt*16 + l16;
            bf16x8 bfg = *(const bf16x8*)&Bs[rb*32 + ((quad ^ ((rb >> 1) & 3)) << 3)];
            acc[nt] = __builtin_amdgcn_mfma_f32_16x16x32_bf16(af, bfg, acc[nt], 0, 0, 0);
        }
        __syncthreads();
    }

#pragma unroll
    for (int nt = 0; nt < 4; nt++) {
        int n = n0 + nt*16 + l16;
        if (n >= XPROJ_N) continue;
#pragma unroll
        for (int rr = 0; rr < 4; rr++) {
            int m = m0 + wave*16 + quad*4 + rr;
            pbuf[((size_t)blockIdx.z * NTOK + m) * XPROJ_N + n] = acc[nt][rr];
        }
    }
}

__global__ __launch_bounds__(256)
void xp_reduce_kernel(const float* __restrict__ pbuf, bf16_t* __restrict__ proj) {
    int i = blockIdx.x * 256 + threadIdx.x;
    if (i >= NTOK * XPROJ_N) return;
    float s = 0.f;
#pragma unroll
    for (int z = 0; z < XP_KS; z++)
        s += pbuf[(size_t)z * NTOK * XPROJ_N + i];
    proj[i] = (bf16_t)s;
}

// ---------------- dt_proj: 64x64 tile, K=48, softplus+bias epilogue ---------
__global__ __launch_bounds__(256)
void gemm_dt(const bf16_t* __restrict__ A, const bf16_t* __restrict__ B,
             bf16_t* __restrict__ C, const float* __restrict__ bias) {
    __shared__ __align__(16) bf16_t As[64*32];
    __shared__ __align__(16) bf16_t Bs[64*32];
    const int tid = threadIdx.x;
    const int m0 = blockIdx.x * 64, n0 = blockIdx.y * 64;
    const int r  = tid >> 2, p8 = (tid & 3) << 3;
    const int q8 = (((tid & 3) ^ ((r >> 1) & 3)) << 3);
    const int wave = tid >> 6, lane = tid & 63;
    const int quad = lane >> 4, l16 = lane & 15;

    f32x4 acc[4] = {{0.f,0.f,0.f,0.f},{0.f,0.f,0.f,0.f},
                    {0.f,0.f,0.f,0.f},{0.f,0.f,0.f,0.f}};

    for (int k0 = 0; k0 < DT_RANK; k0 += 32) {
        int gk = k0 + q8;
        uint4 va = {0u,0u,0u,0u};
        if (gk + 8 <= DT_RANK)
            va = *(const uint4*)(A + (size_t)(m0 + r) * XPROJ_N + gk);
        *(uint4*)&As[r*32 + p8] = va;
        uint4 vb = {0u,0u,0u,0u};
        if (gk + 8 <= DT_RANK)
            vb = *(const uint4*)(B + (size_t)(n0 + r) * DT_RANK + gk);
        *(uint4*)&Bs[r*32 + p8] = vb;

        __syncthreads();
        int ra = wave*16 + l16;
        bf16x8 af = *(const bf16x8*)&As[ra*32 + ((quad ^ ((ra >> 1) & 3)) << 3)];
#pragma unroll
        for (int nt = 0; nt < 4; nt++) {
            int rb = nt*16 + l16;
            bf16x8 bfg = *(const bf16x8*)&Bs[rb*32 + ((quad ^ ((rb >> 1) & 3)) << 3)];
            acc[nt] = __builtin_amdgcn_mfma_f32_16x16x32_bf16(af, bfg, acc[nt], 0, 0, 0);
        }
        __syncthreads();
    }

#pragma unroll
    for (int nt = 0; nt < 4; nt++) {
        int n = n0 + nt*16 + l16;
#pragma unroll
        for (int rr = 0; rr < 4; rr++) {
            int m = m0 + wave*16 + quad*4 + rr;
            float u = acc[nt][rr] + bias[n];
            float sp = (u > 20.f) ? u : log1pf(__expf(u));
            C[(size_t)m * D_INNER + n] = (bf16_t)sp;
        }
    }
}

// ---------------- causal depthwise conv(4) + SiLU, 8 ch/thread vectorized ---
__global__ __launch_bounds__(192)
void conv_silu_kernel(const bf16_t* __restrict__ xz,
                      const float* __restrict__ cw,
                      const float* __restrict__ cb,
                      bf16_t* __restrict__ xc) {
    const int t = blockIdx.x;
    const int l = t & (SEQ - 1);
    const int d = threadIdx.x * 8;       // 192*8 = 1536

    float cwf[32];
#pragma unroll
    for (int q = 0; q < 8; q++)
        *(float4*)&cwf[q*4] = *(const float4*)&cw[d*4 + q*4];

    float acc[8];
    {
        float4 c0 = *(const float4*)&cb[d];
        float4 c1 = *(const float4*)&cb[d+4];
        acc[0]=c0.x; acc[1]=c0.y; acc[2]=c0.z; acc[3]=c0.w;
        acc[4]=c1.x; acc[5]=c1.y; acc[6]=c1.z; acc[7]=c1.w;
    }
#pragma unroll
    for (int k = 0; k < 4; k++) {
        if (l - 3 + k >= 0) {
            bf16x8 v = *(const bf16x8*)&xz[(size_t)(t - 3 + k) * (2*D_INNER) + d];
#pragma unroll
            for (int i = 0; i < 8; i++)
                acc[i] += (float)v[i] * cwf[i*4 + k];
        }
    }
    bf16x8 o;
#pragma unroll
    for (int i = 0; i < 8; i++) {
        float s = acc[i] / (1.f + __expf(-acc[i]));
        o[i] = (bf16_t)s;
    }
    *(bf16x8*)&xc[(size_t)t * D_INNER + d] = o;
}

// ---------------- chunked selective scan, 16 states/thread ----------------
__global__ __launch_bounds__(256)
void scan_part1(const bf16_t* __restrict__ delta,
                const bf16_t* __restrict__ xc,
                const bf16_t* __restrict__ proj,
                const float* __restrict__ A_log,
                float* __restrict__ chunk_h, float* __restrict__ chunk_P) {
    const int tid = threadIdx.x;
    const int d = blockIdx.x * 256 + tid;
    const int c = blockIdx.y;
    const int b = blockIdx.z;
    __shared__ float Bs[LC][D_STATE];
    for (int i = tid; i < LC*D_STATE; i += 256) {
        int l = i >> 4, n = i & 15;
        size_t t = (size_t)b*SEQ + (size_t)c*LC + l;
        Bs[l][n] = (float)proj[t*XPROJ_N + DT_RANK + n];
    }
    __syncthreads();
    float Av2[D_STATE];
#pragma unroll
    for (int n = 0; n < D_STATE; n++)
        Av2[n] = -__expf(A_log[d*D_STATE + n]) * 1.44269504f;   // A[n]*log2(e)
    float s[D_STATE];
#pragma unroll
    for (int n = 0; n < D_STATE; n++) s[n] = 0.f;
    float sdv = 0.f;
    const size_t tbase = (size_t)b*SEQ + (size_t)c*LC;
    for (int l = 0; l < LC; l++) {
        size_t t = tbase + l;
        float dv  = (float)delta[t*D_INNER + d];
        float xcv = (float)xc[t*D_INNER + d];
        float dx = dv * xcv;
        sdv += dv;
#pragma unroll
        for (int n = 0; n < D_STATE; n++) {
            float a = __builtin_amdgcn_exp2f(dv * Av2[n]);
            s[n] = a * s[n] + dx * Bs[l][n];
        }
    }
    size_t base = (((size_t)b*NCHUNK + c)*D_INNER + d)*D_STATE;
#pragma unroll
    for (int n = 0; n < D_STATE; n++) {
        chunk_h[base + n] = s[n];
        chunk_P[base + n] = __builtin_amdgcn_exp2f(Av2[n] * sdv);  // = prod a
    }
}

__global__ __launch_bounds__(256)
void scan_part2(float* __restrict__ chunk_h, const float* __restrict__ chunk_P) {
    int gid = blockIdx.x * 256 + threadIdx.x;      // b*(Di*N) + d*N + n
    int b  = gid / (D_INNER * D_STATE);
    int dn = gid - b * (D_INNER * D_STATE);
    float H = 0.f;
    for (int c = 0; c < NCHUNK; c++) {
        size_t idx = ((size_t)b*NCHUNK + c)*D_INNER*D_STATE + dn;
        float S = chunk_h[idx];
        float P = chunk_P[idx];
        chunk_h[idx] = H;          // becomes the initial state for chunk c
        H = P * H + S;
    }
}

__global__ __launch_bounds__(256)
void scan_part3(const bf16_t* __restrict__ delta,
                const bf16_t* __restrict__ xc,
                const bf16_t* __restrict__ proj,
                const bf16_t* __restrict__ xz,
                const float* __restrict__ A_log,
                const float* __restrict__ Dw,
                const float* __restrict__ chunk_h,
                bf16_t* __restrict__ y) {
    const int tid = threadIdx.x;
    const int d = blockIdx.x * 256 + tid;
    const int c = blockIdx.y;
    const int b = blockIdx.z;
    __shared__ float Bs[LC][D_STATE];
    __shared__ float Cs[LC][D_STATE];
    for (int i = tid; i < LC*D_STATE; i += 256) {
        int l = i >> 4, n = i & 15;
        size_t t = (size_t)b*SEQ + (size_t)c*LC + l;
        Bs[l][n] = (float)proj[t*XPROJ_N + DT_RANK + n];
        Cs[l][n] = (float)proj[t*XPROJ_N + DT_RANK + D_STATE + n];
    }
    __syncthreads();
    float Av2[D_STATE];
#pragma unroll
    for (int n = 0; n < D_STATE; n++)
        Av2[n] = -__expf(A_log[d*D_STATE + n]) * 1.44269504f;
    const float Dv = Dw[d];
    float s[D_STATE];
    size_t base = (((size_t)b*NCHUNK + c)*D_INNER + d)*D_STATE;
#pragma unroll
    for (int n = 0; n < D_STATE; n++) s[n] = chunk_h[base + n];
    const size_t tbase = (size_t)b*SEQ + (size_t)c*LC;
    for (int l = 0; l < LC; l++) {
        size_t t = tbase + l;
        float dv  = (float)delta[t*D_INNER + d];
        float xcv = (float)xc[t*D_INNER + d];
        float dx = dv * xcv;
        float acc = 0.f;
#pragma unroll
        for (int n = 0; n < D_STATE; n++) {
            float a = __builtin_amdgcn_exp2f(dv * Av2[n]);
            s[n] = a * s[n] + dx * Bs[l][n];
            acc += s[n] * Cs[l][n];
        }
        float zf = (float)xz[t*(2*D_INNER) + D_INNER + d];
        float g = zf / (1.f + __expf(-zf));
        y[t*D_INNER + d] = (bf16_t)((acc + xcv * Dv) * g);
    }
}

extern "C" void kernel_launch(void* const* d_in, const int* in_sizes, int n_in,
                              void* d_out, int out_size, void* d_ws, size_t ws_size,
                              hipStream_t stream) {
    const float* x          = (const float*)d_in[0];
    const float* norm_w     = (const float*)d_in[1];
    const float* in_proj_w  = (const float*)d_in[2];
    const float* conv_w     = (const float*)d_in[3];
    const float* conv_b     = (const float*)d_in[4];
    const float* x_proj_w   = (const float*)d_in[5];
    const float* dt_proj_w  = (const float*)d_in[6];
    const float* dt_proj_b  = (const float*)d_in[7];
    const float* A_log      = (const float*)d_in[8];
    const float* Dw         = (const float*)d_in[9];
    const float* out_proj_w = (const float*)d_in[10];

    float* out0 = (float*)d_out;                       // x + out_proj(y)
    float* out1 = out0 + (size_t)NTOK * D_MODEL;       // residual copy

    const size_t n_chunkst = (size_t)NB*NCHUNK*D_INNER*D_STATE;

    char* ws = (char*)d_ws;
    bf16_t* w_in  = (bf16_t*)ws;  ws += (size_t)N_INW * sizeof(bf16_t);
    bf16_t* w_xp  = (bf16_t*)ws;  ws += (size_t)N_XPW * sizeof(bf16_t);
    bf16_t* w_dt  = (bf16_t*)ws;  ws += (size_t)N_DTW * sizeof(bf16_t);
    bf16_t* w_op  = (bf16_t*)ws;  ws += (size_t)N_OPW * sizeof(bf16_t);
    bf16_t* h     = (bf16_t*)ws;  ws += (size_t)NTOK * D_MODEL   * sizeof(bf16_t);
    bf16_t* xz    = (bf16_t*)ws;  ws += (size_t)NTOK * 2*D_INNER * sizeof(bf16_t);
    bf16_t* xc    = (bf16_t*)ws;  ws += (size_t)NTOK * D_INNER   * sizeof(bf16_t);
    bf16_t* proj  = (bf16_t*)ws;  ws += (size_t)NTOK * XPROJ_N   * sizeof(bf16_t);
    bf16_t* delta = (bf16_t*)ws;  ws += (size_t)NTOK * D_INNER   * sizeof(bf16_t);
    bf16_t* y     = (bf16_t*)ws;  ws += (size_t)NTOK * D_INNER   * sizeof(bf16_t);
    float*  ch    = (float*)ws;   ws += n_chunkst * sizeof(float);
    float*  cP    = (float*)ws;   ws += n_chunkst * sizeof(float);
    float*  xppart= (float*)ws;   ws += (size_t)XP_KS * NTOK * XPROJ_N * sizeof(float);

    // 0+1) weight cvt (vectorized) + RMSNorm, one launch
    prep_kernel<<<CVT_BLOCKS + NTOK, 256, 0, stream>>>(
        in_proj_w, w_in, x_proj_w, w_xp, dt_proj_w, w_dt, out_proj_w, w_op,
        x, norm_w, h);
    // 2) in_proj (dbuf 128-tile)
    gemm_nt128<<<dim3(NTOK/128, (2*D_INNER)/128), 256, 0, stream>>>(
        h, D_MODEL, w_in, D_MODEL, xz, 2*D_INNER, D_MODEL);
    // 3) conv + SiLU (8 ch/thread, vectorized)
    conv_silu_kernel<<<NTOK, 192, 0, stream>>>(xz, conv_w, conv_b, xc);
    // 4) x_proj split-K x4 + reduce
    gemm_xp<<<dim3(NTOK/64, 2, XP_KS), 256, 0, stream>>>(xc, w_xp, xppart);
    xp_reduce_kernel<<<(NTOK*XPROJ_N + 255)/256, 256, 0, stream>>>(xppart, proj);
    // 5) dt_proj + softplus (64-tile, K=48)
    gemm_dt<<<dim3(NTOK/64, D_INNER/64), 256, 0, stream>>>(proj, w_dt, delta, dt_proj_b);
    // 6) chunked selective scan
    scan_part1<<<dim3(D_INNER/256, NCHUNK, NB), 256, 0, stream>>>(
        delta, xc, proj, A_log, ch, cP);
    scan_part2<<<(int)((size_t)NB*D_INNER*D_STATE/256), 256, 0, stream>>>(ch, cP);
    scan_part3<<<dim3(D_INNER/256, NCHUNK, NB), 256, 0, stream>>>(
        delta, xc, proj, xz, A_log, Dw, ch, y);
    // 7) out_proj 128x64 dbuf + residual epilogue
    gemm_op<<<dim3(NTOK/128, D_MODEL/64), 256, 0, stream>>>(
        y, w_op, out0, x, out1);
}